// Round 1
// baseline (490.606 us; speedup 1.0000x reference)
//
#include <hip/hip_runtime.h>
#include <math.h>

#define EMBED 1536
#define BN 64
#define XS_STRIDE 1544   // 1536 + 8 pad: row stride 3088 B -> 16B aligned, banks 2-way (free)
#define GS_STRIDE 80     // 64 + 16 pad: row stride 160 B -> 16B aligned

typedef __attribute__((ext_vector_type(8))) short short8;
typedef __attribute__((ext_vector_type(4))) float f32x4;

__device__ inline unsigned short f2bf(float f) {
    union { float f; unsigned u; } c; c.f = f;
    unsigned u = c.u;
    return (unsigned short)((u + 0x7fffu + ((u >> 16) & 1u)) >> 16);
}

// K0a: convert both weight matrices to bf16 into ws (ws re-poisoned every call, so redo every call)
__global__ void conv_kernel(const float* __restrict__ w_down, const float* __restrict__ w_up,
                            unsigned short* __restrict__ wdb, unsigned short* __restrict__ wub) {
    int i = blockIdx.x * blockDim.x + threadIdx.x;
    if (i < BN * EMBED) {
        wdb[i] = f2bf(w_down[i]);
        wub[i] = f2bf(w_up[i]);
    }
}

// K0b: c1[b] = sum_d gamma[d]*w_down[b][d], c2[b] = sum_d beta[d]*w_down[b][d]
__global__ void c12_kernel(const float* __restrict__ w_down, const float* __restrict__ gamma,
                           const float* __restrict__ beta, float* __restrict__ c1,
                           float* __restrict__ c2) {
    int b = blockIdx.x;
    int t = threadIdx.x;
    float s1 = 0.f, s2 = 0.f;
    for (int d = t; d < EMBED; d += 256) {
        float w = w_down[b * EMBED + d];
        s1 += gamma[d] * w;
        s2 += beta[d] * w;
    }
    #pragma unroll
    for (int m = 1; m < 64; m <<= 1) { s1 += __shfl_xor(s1, m); s2 += __shfl_xor(s2, m); }
    __shared__ float r1[4], r2[4];
    int wave = t >> 6, lane = t & 63;
    if (lane == 0) { r1[wave] = s1; r2[wave] = s2; }
    __syncthreads();
    if (t == 0) {
        c1[b] = r1[0] + r1[1] + r1[2] + r1[3];
        c2[b] = r2[0] + r2[1] + r2[2] + r2[3];
    }
}

// Fused: LN-stats + down-proj(MFMA) + GELU + up-proj(MFMA, residual in C) + L2-normalize.
// 16 rows per block, 256 threads (4 waves). LDS ~52 KB -> 3 blocks/CU.
__global__ __launch_bounds__(256) void fused_kernel(
    const float* __restrict__ x, const float* __restrict__ b_down,
    const float* __restrict__ b_up, const float* __restrict__ gamma,
    const unsigned short* __restrict__ wdb, const unsigned short* __restrict__ wub,
    const float* __restrict__ c1, const float* __restrict__ c2,
    float* __restrict__ out)
{
    __shared__ unsigned short xs[16 * XS_STRIDE];  // bf16(x * gamma), raw-x stats folded into epilogue
    __shared__ unsigned short gs[16 * GS_STRIDE];  // bf16 gelu output [row][b]
    __shared__ float mean_s[16], rstd_s[16], sumsq_s[16], inv_s[16];

    const int tid  = threadIdx.x;
    const int wave = tid >> 6, lane = tid & 63;
    const int l16  = lane & 15, quad = lane >> 4;
    const long row0 = (long)blockIdx.x * 16;

    // ---- Phase A: load 4 rows per wave, stats + stage bf16(x*gamma) ----
    const float4* gp = (const float4*)gamma;
    #pragma unroll
    for (int j = 0; j < 4; ++j) {
        int lr = wave * 4 + j;
        const float4* xp = (const float4*)(x + (row0 + lr) * EMBED);
        float4 v[6];
        float s = 0.f, ss = 0.f;
        #pragma unroll
        for (int k = 0; k < 6; ++k) {
            v[k] = xp[lane + 64 * k];
            s  += v[k].x + v[k].y + v[k].z + v[k].w;
            ss += v[k].x * v[k].x + v[k].y * v[k].y + v[k].z * v[k].z + v[k].w * v[k].w;
        }
        #pragma unroll
        for (int m = 1; m < 64; m <<= 1) { s += __shfl_xor(s, m); ss += __shfl_xor(ss, m); }
        float mean = s * (1.f / EMBED);
        float var  = ss * (1.f / EMBED) - mean * mean;
        float rstd = rsqrtf(var + 1e-5f);
        if (lane == 0) { mean_s[lr] = mean; rstd_s[lr] = rstd; sumsq_s[lr] = 0.f; }
        #pragma unroll
        for (int k = 0; k < 6; ++k) {
            float4 g4 = gp[lane + 64 * k];
            ushort4 p;
            p.x = f2bf(v[k].x * g4.x); p.y = f2bf(v[k].y * g4.y);
            p.z = f2bf(v[k].z * g4.z); p.w = f2bf(v[k].w * g4.w);
            *(ushort4*)(&xs[lr * XS_STRIDE + 4 * (lane + 64 * k)]) = p;
        }
    }
    __syncthreads();

    // ---- GEMM1: t[16 rows][16 b per wave] = (x*gamma) . w_down^T, K = 1536 ----
    f32x4 acc = {0.f, 0.f, 0.f, 0.f};
    {
        const unsigned short* arow = &xs[l16 * XS_STRIDE];                 // A[m=l16][k]
        const unsigned short* brow = wdb + (size_t)(wave * 16 + l16) * EMBED; // B^T: W[b=l16][k]
        #pragma unroll 4
        for (int kk = 0; kk < 48; ++kk) {
            int ko = kk * 32 + quad * 8;
            short8 a = *(const short8*)(arow + ko);
            short8 b = *(const short8*)(brow + ko);
            acc = __builtin_amdgcn_mfma_f32_16x16x32_bf16(a, b, acc, 0, 0, 0);
        }
    }
    // epilogue: fold LN scalars, bias, exact GELU -> gs
    {
        int bg = wave * 16 + l16;  // D col = lane&15
        float c1v = c1[bg], c2v = c2[bg], bdv = b_down[bg];
        #pragma unroll
        for (int reg = 0; reg < 4; ++reg) {
            int r = quad * 4 + reg;  // D row = (lane>>4)*4 + reg
            float rs = rstd_s[r];
            float v = rs * acc[reg] - rs * mean_s[r] * c1v + c2v + bdv;
            float g = 0.5f * v * (1.f + erff(v * 0.70710678118654752f));
            gs[r * GS_STRIDE + bg] = f2bf(g);
        }
    }
    __syncthreads();

    // ---- GEMM2: out[16 rows][1536] = g . w_up^T + (x + b_up), K = 64; then row L2-norm ----
    short8 a0 = *(const short8*)(&gs[l16 * GS_STRIDE + quad * 8]);        // A[m=l16][k=0..31]
    short8 a1 = *(const short8*)(&gs[l16 * GS_STRIDE + 32 + quad * 8]);   // A[m=l16][k=32..63]
    float sq[4] = {0.f, 0.f, 0.f, 0.f};

    for (int pass = 0; pass < 2; ++pass) {
        #pragma unroll 2
        for (int t = 0; t < 24; ++t) {
            int d = wave * 384 + t * 16 + l16;   // D col
            float bu = b_up[d];
            f32x4 c;
            #pragma unroll
            for (int reg = 0; reg < 4; ++reg)
                c[reg] = x[(row0 + quad * 4 + reg) * EMBED + d] + bu;  // residual via C operand
            const unsigned short* wrow = wub + (size_t)d * 64;          // w_up[d][b] == B[k=b][n=d]
            short8 b0 = *(const short8*)(wrow + quad * 8);
            short8 b1 = *(const short8*)(wrow + 32 + quad * 8);
            c = __builtin_amdgcn_mfma_f32_16x16x32_bf16(a0, b0, c, 0, 0, 0);
            c = __builtin_amdgcn_mfma_f32_16x16x32_bf16(a1, b1, c, 0, 0, 0);
            if (pass == 0) {
                #pragma unroll
                for (int reg = 0; reg < 4; ++reg) sq[reg] += c[reg] * c[reg];
            } else {
                #pragma unroll
                for (int reg = 0; reg < 4; ++reg)
                    out[(row0 + quad * 4 + reg) * EMBED + d] = c[reg] * inv_s[quad * 4 + reg];
            }
        }
        if (pass == 0) {
            #pragma unroll
            for (int m = 1; m < 16; m <<= 1) {
                #pragma unroll
                for (int reg = 0; reg < 4; ++reg) sq[reg] += __shfl_xor(sq[reg], m);
            }
            if (l16 == 0) {
                #pragma unroll
                for (int reg = 0; reg < 4; ++reg) atomicAdd(&sumsq_s[quad * 4 + reg], sq[reg]);
            }
            __syncthreads();
            if (tid < 16) inv_s[tid] = 1.f / fmaxf(sqrtf(sumsq_s[tid]), 1e-12f);
            __syncthreads();
        }
    }
}

extern "C" void kernel_launch(void* const* d_in, const int* in_sizes, int n_in,
                              void* d_out, int out_size, void* d_ws, size_t ws_size,
                              hipStream_t stream)
{
    const float* x      = (const float*)d_in[0];
    const float* w_down = (const float*)d_in[1];
    const float* b_down = (const float*)d_in[2];
    const float* w_up   = (const float*)d_in[3];
    const float* b_up   = (const float*)d_in[4];
    const float* gamma  = (const float*)d_in[5];
    const float* beta   = (const float*)d_in[6];
    float* out = (float*)d_out;

    const int N = in_sizes[0] / EMBED;  // 32768, multiple of 16

    unsigned short* wdb = (unsigned short*)d_ws;
    unsigned short* wub = wdb + BN * EMBED;
    float* c1 = (float*)(wub + BN * EMBED);
    float* c2 = c1 + BN;

    conv_kernel<<<(BN * EMBED + 255) / 256, 256, 0, stream>>>(w_down, w_up, wdb, wub);
    c12_kernel<<<BN, 256, 0, stream>>>(w_down, gamma, beta, c1, c2);
    fused_kernel<<<N / 16, 256, 0, stream>>>(x, b_down, b_up, gamma, wdb, wub, c1, c2, out);
}

// Round 2
// 415.408 us; speedup vs baseline: 1.1810x; 1.1810x over previous
//
#include <hip/hip_runtime.h>
#include <math.h>

#define EMBED 1536
#define BN 64
#define XS_STRIDE 1544   // shorts; row stride 3088 B -> 16B aligned (ds_read_b128 ok)
#define GS_STRIDE 80     // shorts; row stride 160 B -> 16B aligned

typedef __attribute__((ext_vector_type(8))) short short8;
typedef __attribute__((ext_vector_type(4))) float f32x4;

__device__ inline unsigned short f2bf(float f) {
    union { float f; unsigned u; } c; c.f = f;
    unsigned u = c.u;
    return (unsigned short)((u + 0x7fffu + ((u >> 16) & 1u)) >> 16);
}
__device__ inline float bf2f(unsigned short h) {
    union { unsigned u; float f; } c; c.u = ((unsigned)h) << 16;
    return c.f;
}

// Prep (one kernel): wdg[b][d]=bf16(w_down*gamma), wub=bf16(w_up), c1/c2 reductions.
__global__ void prep_kernel(const float* __restrict__ w_down, const float* __restrict__ w_up,
                            const float* __restrict__ gamma, const float* __restrict__ beta,
                            unsigned short* __restrict__ wdg, unsigned short* __restrict__ wub,
                            float* __restrict__ c1, float* __restrict__ c2) {
    int blk = blockIdx.x;
    if (blk < 384) {
        int i = blk * 256 + threadIdx.x;          // < 64*1536
        int d = i % EMBED;
        wdg[i] = f2bf(w_down[i] * gamma[d]);      // fold LN gamma into down-weights
        wub[i] = f2bf(w_up[i]);
        return;
    }
    int b = blk - 384;                            // 0..63
    int t = threadIdx.x;
    float s1 = 0.f, s2 = 0.f;
    for (int d = t; d < EMBED; d += 256) {
        float w = w_down[b * EMBED + d];
        s1 += gamma[d] * w;
        s2 += beta[d] * w;
    }
    #pragma unroll
    for (int m = 1; m < 64; m <<= 1) { s1 += __shfl_xor(s1, m); s2 += __shfl_xor(s2, m); }
    __shared__ float r1[4], r2[4];
    int wave = t >> 6, lane = t & 63;
    if (lane == 0) { r1[wave] = s1; r2[wave] = s2; }
    __syncthreads();
    if (t == 0) {
        c1[b] = r1[0] + r1[1] + r1[2] + r1[3];
        c2[b] = r2[0] + r2[1] + r2[2] + r2[3];
    }
}

// Fused: LN-stats + down-proj(MFMA) + GELU + up-proj(MFMA, LDS residual in C) + L2-normalize.
// 16 rows/block, 256 threads (4 waves). LDS ~52 KB -> 3 blocks/CU (3 waves/SIMD).
__global__ __launch_bounds__(256, 3) void fused_kernel(
    const float* __restrict__ x, const float* __restrict__ b_down,
    const float* __restrict__ b_up,
    const unsigned short* __restrict__ wdg, const unsigned short* __restrict__ wub,
    const float* __restrict__ c1, const float* __restrict__ c2,
    float* __restrict__ out)
{
    __shared__ unsigned short xs[16 * XS_STRIDE];  // bf16(x): GEMM1 A-operand AND GEMM2 residual
    __shared__ unsigned short gs[16 * GS_STRIDE];  // bf16 gelu output [token][b]
    __shared__ float mean_s[16], rstd_s[16], sumsq_s[16], inv_s[16];

    const int tid  = threadIdx.x;
    const int wave = tid >> 6, lane = tid & 63;
    const int l16  = lane & 15, quad = lane >> 4;
    const long row0 = (long)blockIdx.x * 16;

    // ---- Phase A: batch-load 4 rows/wave (24 outstanding float4 loads), stats, stage bf16(x) ----
    {
        float4 v[4][6];
        #pragma unroll
        for (int j = 0; j < 4; ++j) {
            const float4* xp = (const float4*)(x + (row0 + wave * 4 + j) * EMBED);
            #pragma unroll
            for (int k = 0; k < 6; ++k) v[j][k] = xp[lane + 64 * k];
        }
        #pragma unroll
        for (int j = 0; j < 4; ++j) {
            int lr = wave * 4 + j;
            float s = 0.f, ss = 0.f;
            #pragma unroll
            for (int k = 0; k < 6; ++k) {
                s  += v[j][k].x + v[j][k].y + v[j][k].z + v[j][k].w;
                ss += v[j][k].x * v[j][k].x + v[j][k].y * v[j][k].y
                    + v[j][k].z * v[j][k].z + v[j][k].w * v[j][k].w;
            }
            #pragma unroll
            for (int m = 1; m < 64; m <<= 1) { s += __shfl_xor(s, m); ss += __shfl_xor(ss, m); }
            float mean = s * (1.f / EMBED);
            float var  = ss * (1.f / EMBED) - mean * mean;
            if (lane == 0) {
                mean_s[lr] = mean;
                rstd_s[lr] = rsqrtf(var + 1e-5f);
                sumsq_s[lr] = 0.f;
            }
            #pragma unroll
            for (int k = 0; k < 6; ++k) {
                ushort4 p;
                p.x = f2bf(v[j][k].x); p.y = f2bf(v[j][k].y);
                p.z = f2bf(v[j][k].z); p.w = f2bf(v[j][k].w);
                *(ushort4*)(&xs[lr * XS_STRIDE + 4 * (lane + 64 * k)]) = p;
            }
        }
    }
    __syncthreads();

    // ---- GEMM1: t[token 16][b 16/wave] = x . (gamma*w_down)^T, K=1536 ----
    f32x4 acc = {0.f, 0.f, 0.f, 0.f};
    {
        const unsigned short* arow = &xs[l16 * XS_STRIDE];                    // A[m=l16][k]
        const unsigned short* brow = wdg + (size_t)(wave * 16 + l16) * EMBED; // B^T: W[b=l16][k]
        #pragma unroll 4
        for (int kk = 0; kk < 48; ++kk) {
            int ko = kk * 32 + quad * 8;
            short8 a = *(const short8*)(arow + ko);
            short8 b = *(const short8*)(brow + ko);
            acc = __builtin_amdgcn_mfma_f32_16x16x32_bf16(a, b, acc, 0, 0, 0);
        }
    }
    // epilogue: LN scalar corrections + bias + exact GELU -> gs[token][b]
    {
        int bg = wave * 16 + l16;  // D col = lane&15
        float c1v = c1[bg], c2v = c2[bg], bdv = b_down[bg];
        #pragma unroll
        for (int reg = 0; reg < 4; ++reg) {
            int r = quad * 4 + reg;  // D row = (lane>>4)*4 + reg
            float rs = rstd_s[r];
            float v = rs * acc[reg] - rs * mean_s[r] * c1v + c2v + bdv;
            float g = 0.5f * v * (1.f + erff(v * 0.70710678118654752f));
            gs[r * GS_STRIDE + bg] = f2bf(g);
        }
    }
    __syncthreads();

    // ---- GEMM2 (transposed tile): D[m=d 16][n=token 16] = w_up_tile . g^T + (x + b_up) ----
    // b-frag (shared by all waves): B[k=quad*8+j][n=l16] = g[token=l16][k]
    short8 gb0 = *(const short8*)(&gs[l16 * GS_STRIDE + quad * 8]);
    short8 gb1 = *(const short8*)(&gs[l16 * GS_STRIDE + 32 + quad * 8]);
    const int dbase = wave * 384;
    f32x4 cc[24];
    float sqs = 0.f;
    #pragma unroll
    for (int t = 0; t < 24; ++t) {
        int d0 = dbase + t * 16;
        int dm = d0 + quad * 4;                                  // C rows: 4 consecutive d
        float4 bu = *(const float4*)(b_up + dm);
        ushort4 rx = *(const ushort4*)(&xs[l16 * XS_STRIDE + dm]); // residual: token l16, d dm..dm+3
        f32x4 c;
        c[0] = bf2f(rx.x) + bu.x;
        c[1] = bf2f(rx.y) + bu.y;
        c[2] = bf2f(rx.z) + bu.z;
        c[3] = bf2f(rx.w) + bu.w;
        const unsigned short* wrow = wub + (size_t)(d0 + l16) * 64;  // A[m=l16][k] = w_up[d0+l16][k]
        short8 a0 = *(const short8*)(wrow + quad * 8);
        short8 a1 = *(const short8*)(wrow + 32 + quad * 8);
        c = __builtin_amdgcn_mfma_f32_16x16x32_bf16(a0, gb0, c, 0, 0, 0);
        c = __builtin_amdgcn_mfma_f32_16x16x32_bf16(a1, gb1, c, 0, 0, 0);
        cc[t] = c;
        sqs += c[0] * c[0] + c[1] * c[1] + c[2] * c[2] + c[3] * c[3];
    }
    // per-token sumsq: lane's partial is for token l16 over this wave's d-range; sum over quads,
    // then one LDS atomic per (wave, token).
    sqs += __shfl_xor(sqs, 16);
    sqs += __shfl_xor(sqs, 32);
    if (lane < 16) atomicAdd(&sumsq_s[l16], sqs);
    __syncthreads();
    if (tid < 16) inv_s[tid] = 1.f / fmaxf(sqrtf(sumsq_s[tid]), 1e-12f);
    __syncthreads();

    const float inv = inv_s[l16];
    float* orow = out + (row0 + l16) * EMBED;
    #pragma unroll
    for (int t = 0; t < 24; ++t) {
        int dm = dbase + t * 16 + quad * 4;
        f32x4 c = cc[t];
        float4 o;
        o.x = c[0] * inv; o.y = c[1] * inv; o.z = c[2] * inv; o.w = c[3] * inv;
        *(float4*)(orow + dm) = o;   // 16 B/lane store
    }
}

extern "C" void kernel_launch(void* const* d_in, const int* in_sizes, int n_in,
                              void* d_out, int out_size, void* d_ws, size_t ws_size,
                              hipStream_t stream)
{
    const float* x      = (const float*)d_in[0];
    const float* w_down = (const float*)d_in[1];
    const float* b_down = (const float*)d_in[2];
    const float* w_up   = (const float*)d_in[3];
    const float* b_up   = (const float*)d_in[4];
    const float* gamma  = (const float*)d_in[5];
    const float* beta   = (const float*)d_in[6];
    float* out = (float*)d_out;

    const int N = in_sizes[0] / EMBED;  // 32768, multiple of 16

    unsigned short* wdg = (unsigned short*)d_ws;
    unsigned short* wub = wdg + BN * EMBED;
    float* c1 = (float*)(wub + BN * EMBED);
    float* c2 = c1 + BN;

    prep_kernel<<<384 + BN, 256, 0, stream>>>(w_down, w_up, gamma, beta, wdg, wub, c1, c2);
    fused_kernel<<<N / 16, 256, 0, stream>>>(x, b_down, b_up, wdg, wub, c1, c2, out);
}